// Round 3
// baseline (783.651 us; speedup 1.0000x reference)
//
#include <hip/hip_runtime.h>
#include <cstdint>

#define N_NODES 524288
#define E_EDGES 8388608
#define F_IN 128
#define HID 8
#define B_GRAPHS 64
#define NPG 8192
#define NPG_SHIFT 13

// ---- single-level fixed-capacity counting sort ----
#define BUCKETS 256
#define BSHIFT 11              // node >> 11 -> bucket
#define BNODES 2048            // nodes per bucket
#define BMASK 2047
#define SBLK 512               // scatter blocks
#define STHREADS 512
#define EPB (E_EDGES / SBLK)   // 16384 edges per scatter block
#define CAP 160                // per-(bucket,block) sub-segment capacity (mean 64, +12 sigma)
#define EB_STRIDE (SBLK * CAP) // 81920 dwords of ebuf per bucket
#define CSR_CAP 36864          // per-bucket csr region (mean 32768, +22 sigma)

// ---------------- clear the 4 bitmap planes (256 KB) ----------------
__global__ void clear_kernel(int4* __restrict__ p) {
    p[blockIdx.x * blockDim.x + threadIdx.x] = make_int4(0, 0, 0, 0);
}

// ---- scatter: partition edges into per-(bucket,block) fixed-cap runs ----
__global__ __launch_bounds__(STHREADS) void scatter_kernel(
        const int* __restrict__ src, const int* __restrict__ dst,
        unsigned int* __restrict__ ebuf, int* __restrict__ sc) {
    __shared__ int cur[BUCKETS];
    int t = threadIdx.x;
    if (t < BUCKETS) cur[t] = 0;
    __syncthreads();
    int eb = blockIdx.x * EPB;
    size_t blkoff = (size_t)blockIdx.x * CAP;
    #pragma unroll 4
    for (int k = 0; k < EPB / STHREADS; ++k) {
        int e = eb + k * STHREADS + t;
        int d = dst[e];
        int s = src[e];
        int b = d >> BSHIFT;
        int p = atomicAdd(&cur[b], 1);
        if (p < CAP)
            ebuf[(size_t)b * EB_STRIDE + blkoff + p] =
                ((unsigned int)(d & BMASK) << 19) | (unsigned int)s;
    }
    __syncthreads();
    if (t < BUCKETS) sc[t * SBLK + blockIdx.x] = (cur[t] < CAP) ? cur[t] : CAP;
}

// ---- build: per-bucket fine counting sort -> rowptr(int2), dis, csr ----
__global__ __launch_bounds__(256) void build_kernel(const unsigned int* __restrict__ ebuf,
                                                    const int* __restrict__ sc,
                                                    int2* __restrict__ rowptr,
                                                    float* __restrict__ dis,
                                                    int* __restrict__ csr) {
    __shared__ int scs[SBLK];
    __shared__ int cnt[BNODES];
    __shared__ int cur[BNODES];
    __shared__ int tsum[256];
    int t = threadIdx.x;
    int b = blockIdx.x;
    for (int j = t; j < SBLK; j += 256) scs[j] = sc[b * SBLK + j];
    for (int j = t; j < BNODES; j += 256) cnt[j] = 0;
    __syncthreads();
    const unsigned int* eb = ebuf + (size_t)b * EB_STRIDE;
    int wv = t >> 6, ln = t & 63;
    // count pass: wave-cooperative coalesced reads of each sub-segment
    for (int ss = wv; ss < SBLK; ss += 4) {
        int n = scs[ss];
        const unsigned int* p = eb + ss * CAP;
        for (int k = ln; k < n; k += 64)
            atomicAdd(&cnt[p[k] >> 19], 1);
    }
    __syncthreads();
    // exclusive scan of 2048 bins, 8 per thread
    int v[8], loc[8], s = 0;
    #pragma unroll
    for (int k2 = 0; k2 < 8; ++k2) { v[k2] = cnt[t * 8 + k2]; loc[k2] = s; s += v[k2]; }
    tsum[t] = s;
    __syncthreads();
    for (int o = 1; o < 256; o <<= 1) {
        int y = (t >= o) ? tsum[t - o] : 0;
        __syncthreads();
        tsum[t] += y;
        __syncthreads();
    }
    int off = (t == 0) ? 0 : tsum[t - 1];
    int cbase = b * CSR_CAP;
    #pragma unroll
    for (int k2 = 0; k2 < 8; ++k2) {
        int j = t * 8 + k2;
        int st = off + loc[k2];
        cur[j] = st;
        rowptr[b * BNODES + j] = make_int2(cbase + st, cbase + st + v[k2]);
        dis[b * BNODES + j] = rsqrtf((float)v[k2] + 1.0f);
    }
    __syncthreads();
    // scatter pass
    for (int ss = wv; ss < SBLK; ss += 4) {
        int n = scs[ss];
        const unsigned int* p = eb + ss * CAP;
        for (int k = ln; k < n; k += 64) {
            unsigned int w = p[k];
            int ps = atomicAdd(&cur[w >> 19], 1);
            csr[cbase + ps] = (int)(w & 0x7FFFFu);
        }
    }
}

// ---------------- BFS1: targets -> planes, mark in-nbrs (S1) ----------------
__global__ void bfs1_kernel(const int* __restrict__ tgt, const int2* __restrict__ rowptr,
                            const int* __restrict__ csr,
                            unsigned int* __restrict__ bm1, unsigned int* __restrict__ bm2,
                            unsigned int* __restrict__ bm3, unsigned int* __restrict__ bmT) {
    int g = threadIdx.x;
    if (g >= B_GRAPHS) return;
    int t = g * NPG + tgt[g];
    atomicOr(&bmT[t >> 5], 1u << (t & 31));
    atomicOr(&bm1[t >> 5], 1u << (t & 31));
    atomicOr(&bm2[t >> 5], 1u << (t & 31));
    atomicOr(&bm3[t >> 5], 1u << (t & 31));
    int2 r = rowptr[t];
    for (int k = r.x; k < r.y; ++k) {
        int s = csr[k];
        atomicOr(&bm1[s >> 5], 1u << (s & 31));
        atomicOr(&bm2[s >> 5], 1u << (s & 31));
        atomicOr(&bm3[s >> 5], 1u << (s & 31));
    }
}

// ---------------- BFS2: plane1 nodes -> mark in-nbrs into planes 2,3 --------
__global__ void bfs2_kernel(const int2* __restrict__ rowptr, const int* __restrict__ csr,
                            const unsigned int* __restrict__ bm1,
                            unsigned int* __restrict__ bm2, unsigned int* __restrict__ bm3) {
    int i = blockIdx.x * blockDim.x + threadIdx.x;
    if (!((bm1[i >> 5] >> (i & 31)) & 1u)) return;
    int2 r = rowptr[i];
    for (int k = r.x; k < r.y; ++k) {
        int s = csr[k];
        atomicOr(&bm2[s >> 5], 1u << (s & 31));
        atomicOr(&bm3[s >> 5], 1u << (s & 31));
    }
}

// ---------------- BFS3: plane2 nodes -> mark in-nbrs into plane 3 -----------
__global__ void bfs3_kernel(const int2* __restrict__ rowptr, const int* __restrict__ csr,
                            const unsigned int* __restrict__ bm2,
                            unsigned int* __restrict__ bm3) {
    int i = blockIdx.x * blockDim.x + threadIdx.x;
    if (!((bm2[i >> 5] >> (i & 31)) & 1u)) return;
    int2 r = rowptr[i];
    for (int k = r.x; k < r.y; ++k) {
        int s = csr[k];
        atomicOr(&bm3[s >> 5], 1u << (s & 31));
    }
}

// ---------------- hps = (x @ W1) * dis, only at plane3 nodes ----------------
__global__ void mm1s_kernel(const float* __restrict__ x, const float* __restrict__ W1,
                            const unsigned int* __restrict__ bm3,
                            const float* __restrict__ dis, float* __restrict__ hps) {
    __shared__ float w[F_IN * HID];
    for (int t = threadIdx.x; t < F_IN * HID; t += blockDim.x) w[t] = W1[t];
    __syncthreads();
    int row = blockIdx.x * blockDim.x + threadIdx.x;
    if (!((bm3[row >> 5] >> (row & 31)) & 1u)) return;
    const float4* xr = (const float4*)(x + (size_t)row * F_IN);
    float acc[HID] = {0.f,0.f,0.f,0.f,0.f,0.f,0.f,0.f};
    #pragma unroll 8
    for (int it = 0; it < F_IN / 4; ++it) {
        float4 xv = xr[it];
        const float* wr = &w[it * 4 * HID];
        #pragma unroll
        for (int j = 0; j < HID; ++j)
            acc[j] += xv.x * wr[j] + xv.y * wr[HID + j] + xv.z * wr[2 * HID + j] + xv.w * wr[3 * HID + j];
    }
    float di = dis[row];
    float4* o = (float4*)(hps + (size_t)row * HID);
    o[0] = make_float4(acc[0] * di, acc[1] * di, acc[2] * di, acc[3] * di);
    o[1] = make_float4(acc[4] * di, acc[5] * di, acc[6] * di, acc[7] * di);
}

// ---- gather1 (plane2 nodes): x1 = relu(di*(sum hps[s] + hps[i]) + b1);
//      hps2 = (x1 @ W2) * di; targets stash x1 row into x1t ------------------
__global__ void gather1_kernel(const int2* __restrict__ rowptr, const int* __restrict__ csr,
                               const float* __restrict__ dis, const float* __restrict__ hps,
                               const unsigned int* __restrict__ bm2,
                               const unsigned int* __restrict__ bmT,
                               const float* __restrict__ b1v, const float* __restrict__ W2,
                               float* __restrict__ hps2, float* __restrict__ x1t) {
    __shared__ float w[HID * HID];
    if (threadIdx.x < HID * HID) w[threadIdx.x] = W2[threadIdx.x];
    __syncthreads();
    int i = blockIdx.x * blockDim.x + threadIdx.x;
    if (!((bm2[i >> 5] >> (i & 31)) & 1u)) return;
    float di = dis[i];
    int2 r = rowptr[i];
    float acc[HID] = {0.f,0.f,0.f,0.f,0.f,0.f,0.f,0.f};
    for (int k = r.x; k < r.y; ++k) {
        int s = csr[k];
        const float4* h = (const float4*)(hps + (size_t)s * HID);
        float4 a = h[0], b = h[1];
        acc[0] += a.x; acc[1] += a.y; acc[2] += a.z; acc[3] += a.w;
        acc[4] += b.x; acc[5] += b.y; acc[6] += b.z; acc[7] += b.w;
    }
    const float4* hs = (const float4*)(hps + (size_t)i * HID);
    float4 h0 = hs[0], h1 = hs[1];
    float v[HID];
    v[0] = fmaxf(di * (acc[0] + h0.x) + b1v[0], 0.f);
    v[1] = fmaxf(di * (acc[1] + h0.y) + b1v[1], 0.f);
    v[2] = fmaxf(di * (acc[2] + h0.z) + b1v[2], 0.f);
    v[3] = fmaxf(di * (acc[3] + h0.w) + b1v[3], 0.f);
    v[4] = fmaxf(di * (acc[4] + h1.x) + b1v[4], 0.f);
    v[5] = fmaxf(di * (acc[5] + h1.y) + b1v[5], 0.f);
    v[6] = fmaxf(di * (acc[6] + h1.z) + b1v[6], 0.f);
    v[7] = fmaxf(di * (acc[7] + h1.w) + b1v[7], 0.f);
    if ((bmT[i >> 5] >> (i & 31)) & 1u) {
        float* xt = x1t + (size_t)(i >> NPG_SHIFT) * HID;
        #pragma unroll
        for (int j = 0; j < HID; ++j) xt[j] = v[j];
    }
    float o[HID];
    #pragma unroll
    for (int j = 0; j < HID; ++j) {
        float sj = 0.f;
        #pragma unroll
        for (int k = 0; k < HID; ++k) sj += v[k] * w[k * HID + j];
        o[j] = sj * di;
    }
    float4* op = (float4*)(hps2 + (size_t)i * HID);
    op[0] = make_float4(o[0], o[1], o[2], o[3]);
    op[1] = make_float4(o[4], o[5], o[6], o[7]);
}

// ---- gather2 (plane1 nodes): x2 = relu(di*(sum hps2[s] + hps2[i]) + b2) ----
__global__ void gather2_kernel(const int2* __restrict__ rowptr, const int* __restrict__ csr,
                               const float* __restrict__ dis, const float* __restrict__ hps2,
                               const unsigned int* __restrict__ bm1,
                               const float* __restrict__ b2v, float* __restrict__ x2) {
    int i = blockIdx.x * blockDim.x + threadIdx.x;
    if (!((bm1[i >> 5] >> (i & 31)) & 1u)) return;
    float di = dis[i];
    int2 r = rowptr[i];
    float acc[HID] = {0.f,0.f,0.f,0.f,0.f,0.f,0.f,0.f};
    for (int k = r.x; k < r.y; ++k) {
        int s = csr[k];
        const float4* h = (const float4*)(hps2 + (size_t)s * HID);
        float4 a = h[0], b = h[1];
        acc[0] += a.x; acc[1] += a.y; acc[2] += a.z; acc[3] += a.w;
        acc[4] += b.x; acc[5] += b.y; acc[6] += b.z; acc[7] += b.w;
    }
    const float4* hs = (const float4*)(hps2 + (size_t)i * HID);
    float4 h0 = hs[0], h1 = hs[1];
    float4* xo = (float4*)(x2 + (size_t)i * HID);
    xo[0] = make_float4(fmaxf(di * (acc[0] + h0.x) + b2v[0], 0.f),
                        fmaxf(di * (acc[1] + h0.y) + b2v[1], 0.f),
                        fmaxf(di * (acc[2] + h0.z) + b2v[2], 0.f),
                        fmaxf(di * (acc[3] + h0.w) + b2v[3], 0.f));
    xo[1] = make_float4(fmaxf(di * (acc[4] + h1.x) + b2v[4], 0.f),
                        fmaxf(di * (acc[5] + h1.y) + b2v[5], 0.f),
                        fmaxf(di * (acc[6] + h1.z) + b2v[6], 0.f),
                        fmaxf(di * (acc[7] + h1.w) + b2v[7], 0.f));
}

// ---- head: x3 at target via csr row + feats + MLP ----
__global__ void headf_kernel(const int* __restrict__ tgt, const int2* __restrict__ rowptr,
                             const int* __restrict__ csr, const float* __restrict__ dis,
                             const float* __restrict__ x1t, const float* __restrict__ x2,
                             const float* __restrict__ W3, const float* __restrict__ b3,
                             const float* __restrict__ Wl1, const float* __restrict__ bl1,
                             const float* __restrict__ Wl2, const float* __restrict__ bl2,
                             float* __restrict__ out) {
    int g = threadIdx.x;
    if (g >= B_GRAPHS) return;
    size_t t = (size_t)g * NPG + tgt[g];
    float di = dis[t];
    float w3[HID];
    #pragma unroll
    for (int j = 0; j < HID; ++j) w3[j] = W3[j];
    float f[17];
    #pragma unroll
    for (int j = 0; j < HID; ++j) f[j] = x1t[(size_t)g * HID + j];
    #pragma unroll
    for (int j = 0; j < HID; ++j) f[8 + j] = x2[t * HID + j];
    int2 r = rowptr[t];
    float a3 = 0.f;
    for (int k = r.x; k < r.y; ++k) {
        int s = csr[k];
        float h = 0.f;
        #pragma unroll
        for (int j = 0; j < HID; ++j) h += x2[(size_t)s * HID + j] * w3[j];
        a3 += h * dis[s];
    }
    float h3 = 0.f;
    #pragma unroll
    for (int j = 0; j < HID; ++j) h3 += f[8 + j] * w3[j];
    f[16] = fmaxf(a3 * di + h3 * di * di + b3[0], 0.f);
    float o0 = bl2[0], o1 = bl2[1];
    #pragma unroll
    for (int j = 0; j < 16; ++j) {
        float z = bl1[j];
        #pragma unroll
        for (int k = 0; k < 17; ++k) z += f[k] * Wl1[k * 16 + j];
        z = fmaxf(z, 0.f);
        o0 += z * Wl2[j * 2 + 0];
        o1 += z * Wl2[j * 2 + 1];
    }
    out[g * 2 + 0] = o0;
    out[g * 2 + 1] = o1;
}

extern "C" void kernel_launch(void* const* d_in, const int* in_sizes, int n_in,
                              void* d_out, int out_size, void* d_ws, size_t ws_size,
                              hipStream_t stream) {
    const float* x  = (const float*)d_in[0];
    const int* ei   = (const int*)d_in[1];
    const int* src  = ei;
    const int* dst  = ei + E_EDGES;
    const int* tid  = (const int*)d_in[2];
    const float* W1 = (const float*)d_in[3];
    const float* b1 = (const float*)d_in[4];
    const float* W2 = (const float*)d_in[5];
    const float* b2 = (const float*)d_in[6];
    const float* W3 = (const float*)d_in[7];
    const float* b3 = (const float*)d_in[8];
    const float* Wl1 = (const float*)d_in[9];
    const float* bl1 = (const float*)d_in[10];
    const float* Wl2 = (const float*)d_in[11];
    const float* bl2 = (const float*)d_in[12];
    float* out = (float*)d_out;

    char* ws = (char*)d_ws;
    size_t off = 0;
    auto alloc = [&](size_t bytes) {
        void* p = ws + off;
        off += (bytes + 255) & ~(size_t)255;
        return p;
    };
    // bitmap planes (cleared each run, contiguous 256 KB)
    unsigned int* bm1 = (unsigned int*)alloc(65536);
    unsigned int* bm2 = (unsigned int*)alloc(65536);
    unsigned int* bm3 = (unsigned int*)alloc(65536);
    unsigned int* bmT = (unsigned int*)alloc(65536);
    float* x1t  = (float*)alloc((size_t)B_GRAPHS * HID * 4);            // 2 KB
    int* sc     = (int*)alloc((size_t)BUCKETS * SBLK * 4);              // 512 KB (fully rewritten each run)
    int2* rowptr = (int2*)alloc((size_t)N_NODES * 8);                   // 4 MB
    float* dis  = (float*)alloc((size_t)N_NODES * 4);                   // 2 MB
    unsigned int* ebuf = (unsigned int*)alloc((size_t)BUCKETS * EB_STRIDE * 4); // 84 MB
    int* csr    = (int*)alloc((size_t)BUCKETS * CSR_CAP * 4);           // 37.75 MB
    float* hps  = (float*)alloc((size_t)N_NODES * HID * 4);             // 16 MB
    float* hps2 = (float*)alloc((size_t)N_NODES * HID * 4);             // 16 MB
    float* x2 = hps;            // hps dead after gather1; reuse for x2
    (void)ws_size;

    clear_kernel<<<64, 256, 0, stream>>>((int4*)bm1);   // 16384 int4 = 4 planes
    scatter_kernel<<<SBLK, STHREADS, 0, stream>>>(src, dst, ebuf, sc);
    build_kernel<<<BUCKETS, 256, 0, stream>>>(ebuf, sc, rowptr, dis, csr);
    bfs1_kernel<<<1, 64, 0, stream>>>(tid, rowptr, csr, bm1, bm2, bm3, bmT);
    bfs2_kernel<<<2048, 256, 0, stream>>>(rowptr, csr, bm1, bm2, bm3);
    bfs3_kernel<<<2048, 256, 0, stream>>>(rowptr, csr, bm2, bm3);
    mm1s_kernel<<<2048, 256, 0, stream>>>(x, W1, bm3, dis, hps);
    gather1_kernel<<<2048, 256, 0, stream>>>(rowptr, csr, dis, hps, bm2, bmT, b1, W2, hps2, x1t);
    gather2_kernel<<<2048, 256, 0, stream>>>(rowptr, csr, dis, hps2, bm1, b2, x2);
    headf_kernel<<<1, 64, 0, stream>>>(tid, rowptr, csr, dis, x1t, x2,
                                       W3, b3, Wl1, bl1, Wl2, bl2, out);
}

// Round 4
// 752.702 us; speedup vs baseline: 1.0411x; 1.0411x over previous
//
#include <hip/hip_runtime.h>
#include <cstdint>

#define N_NODES 524288
#define E_EDGES 8388608
#define F_IN 128
#define HID 8
#define B_GRAPHS 64
#define NPG 8192
#define NPG_SHIFT 13

// ---- bucketed degree count ----
#define BUCKETS 256
#define BSHIFT 11              // node >> 11 -> bucket
#define BNODES 2048            // nodes per bucket
#define BMASK 2047
#define SBLK 512               // scatter blocks
#define STHREADS 512
#define EPB (E_EDGES / SBLK)   // 16384 edges per scatter block
#define CAP 160                // per-(bucket,block) capacity (mean 64, +12 sigma) - proven r3
#define EB_STRIDE (SBLK * CAP) // 81920 dwords per bucket

#define SWBLK 8192             // sweep blocks: 8192 x 256 x int4 = 8.4M edges

// ---------------- clear bitmaps (256 KB) + cur (2 MB) ----------------
__global__ void clear_kernel(int4* __restrict__ p) {
    p[blockIdx.x * blockDim.x + threadIdx.x] = make_int4(0, 0, 0, 0);
}

// ---------------- init: mark targets in all planes ----------------
__global__ void init_kernel(const int* __restrict__ tgt,
                            unsigned int* __restrict__ bmT, unsigned int* __restrict__ bmP1,
                            unsigned int* __restrict__ bmP2, unsigned int* __restrict__ bmP3) {
    int g = threadIdx.x;
    if (g >= B_GRAPHS) return;
    int t = g * NPG + tgt[g];
    atomicOr(&bmT[t >> 5], 1u << (t & 31));
    atomicOr(&bmP1[t >> 5], 1u << (t & 31));
    atomicOr(&bmP2[t >> 5], 1u << (t & 31));
    atomicOr(&bmP3[t >> 5], 1u << (t & 31));
}

// ---- scatter: partition dst ids into per-(bucket,block) fixed-cap runs ----
__global__ __launch_bounds__(STHREADS) void scatter_kernel(
        const int* __restrict__ dst,
        unsigned int* __restrict__ ebuf, int* __restrict__ sc) {
    __shared__ int cur[BUCKETS];
    int t = threadIdx.x;
    if (t < BUCKETS) cur[t] = 0;
    __syncthreads();
    int eb = blockIdx.x * EPB;
    size_t blkoff = (size_t)blockIdx.x * CAP;
    #pragma unroll 4
    for (int k = 0; k < EPB / STHREADS; ++k) {
        int d = dst[eb + k * STHREADS + t];
        int b = d >> BSHIFT;
        int p = atomicAdd(&cur[b], 1);
        if (p < CAP)
            ebuf[(size_t)b * EB_STRIDE + blkoff + p] = (unsigned int)(d & BMASK);
    }
    __syncthreads();
    if (t < BUCKETS) sc[t * SBLK + blockIdx.x] = (cur[t] < CAP) ? cur[t] : CAP;
}

// ---- count: per-bucket fine histogram -> rowptr2 (local int2), dis, btot ----
__global__ __launch_bounds__(256) void count_kernel(const unsigned int* __restrict__ ebuf,
                                                    const int* __restrict__ sc,
                                                    int2* __restrict__ rowptr2,
                                                    float* __restrict__ dis,
                                                    int* __restrict__ btot) {
    __shared__ int scs[SBLK];
    __shared__ int cnt[BNODES];
    __shared__ int tsum[256];
    int t = threadIdx.x;
    int b = blockIdx.x;
    for (int j = t; j < SBLK; j += 256) scs[j] = sc[b * SBLK + j];
    for (int j = t; j < BNODES; j += 256) cnt[j] = 0;
    __syncthreads();
    const unsigned int* eb = ebuf + (size_t)b * EB_STRIDE;
    int wv = t >> 6, ln = t & 63;
    for (int ss = wv; ss < SBLK; ss += 4) {
        int n = scs[ss];
        const unsigned int* p = eb + ss * CAP;
        for (int k = ln; k < n; k += 64)
            atomicAdd(&cnt[p[k]], 1);
    }
    __syncthreads();
    // exclusive scan of 2048 bins, 8 per thread
    int v[8], loc[8], s = 0;
    #pragma unroll
    for (int k2 = 0; k2 < 8; ++k2) { v[k2] = cnt[t * 8 + k2]; loc[k2] = s; s += v[k2]; }
    tsum[t] = s;
    __syncthreads();
    for (int o = 1; o < 256; o <<= 1) {
        int y = (t >= o) ? tsum[t - o] : 0;
        __syncthreads();
        tsum[t] += y;
        __syncthreads();
    }
    int off = (t == 0) ? 0 : tsum[t - 1];
    #pragma unroll
    for (int k2 = 0; k2 < 8; ++k2) {
        int j = t * 8 + k2;
        int st = off + loc[k2];
        rowptr2[b * BNODES + j] = make_int2(st, st + v[k2]);
        dis[b * BNODES + j] = rsqrtf((float)v[k2] + 1.0f);
    }
    if (t == 255) btot[b] = off + s;
}

// ---- basescan: exclusive scan of 256 bucket totals -> bbase ----
__global__ void basescan_kernel(const int* __restrict__ btot, int* __restrict__ bbase) {
    __shared__ int tsum[256];
    int t = threadIdx.x;
    int v = btot[t];
    tsum[t] = v;
    __syncthreads();
    for (int o = 1; o < 256; o <<= 1) {
        int y = (t >= o) ? tsum[t - o] : 0;
        __syncthreads();
        tsum[t] += y;
        __syncthreads();
    }
    int off = tsum[t] - v;
    bbase[t] = off;
    if (t == 255) bbase[256] = off + v;
}

// ---- sweep1: d in T -> mark s into P1,P2,P3 ----
__global__ __launch_bounds__(256) void sweep1_kernel(
        const int* __restrict__ src, const int* __restrict__ dst,
        const unsigned int* __restrict__ bmT,
        unsigned int* __restrict__ bmP1, unsigned int* __restrict__ bmP2,
        unsigned int* __restrict__ bmP3) {
    int i = blockIdx.x * 256 + threadIdx.x;
    int4 d4 = ((const int4*)dst)[i];
    int e = i * 4;
    #pragma unroll
    for (int k = 0; k < 4; ++k) {
        int d = (k == 0) ? d4.x : (k == 1) ? d4.y : (k == 2) ? d4.z : d4.w;
        if ((bmT[d >> 5] >> (d & 31)) & 1u) {
            int s = src[e + k];
            atomicOr(&bmP1[s >> 5], 1u << (s & 31));
            atomicOr(&bmP2[s >> 5], 1u << (s & 31));
            atomicOr(&bmP3[s >> 5], 1u << (s & 31));
        }
    }
}

// ---- sweep2: d in P1 -> mark s into P2,P3 ----
__global__ __launch_bounds__(256) void sweep2_kernel(
        const int* __restrict__ src, const int* __restrict__ dst,
        const unsigned int* __restrict__ bmP1,
        unsigned int* __restrict__ bmP2, unsigned int* __restrict__ bmP3) {
    int i = blockIdx.x * 256 + threadIdx.x;
    int4 d4 = ((const int4*)dst)[i];
    int e = i * 4;
    #pragma unroll
    for (int k = 0; k < 4; ++k) {
        int d = (k == 0) ? d4.x : (k == 1) ? d4.y : (k == 2) ? d4.z : d4.w;
        if ((bmP1[d >> 5] >> (d & 31)) & 1u) {
            int s = src[e + k];
            atomicOr(&bmP2[s >> 5], 1u << (s & 31));
            atomicOr(&bmP3[s >> 5], 1u << (s & 31));
        }
    }
}

// ---- sweep3: d in P2 -> mark s into P3, scatter edge into CSR slot ----
__global__ __launch_bounds__(256) void sweep3_kernel(
        const int* __restrict__ src, const int* __restrict__ dst,
        const unsigned int* __restrict__ bmP2, unsigned int* __restrict__ bmP3,
        const int2* __restrict__ rowptr2, const int* __restrict__ bbase,
        int* __restrict__ cur, int* __restrict__ csr) {
    int i = blockIdx.x * 256 + threadIdx.x;
    int4 d4 = ((const int4*)dst)[i];
    int e = i * 4;
    #pragma unroll
    for (int k = 0; k < 4; ++k) {
        int d = (k == 0) ? d4.x : (k == 1) ? d4.y : (k == 2) ? d4.z : d4.w;
        if ((bmP2[d >> 5] >> (d & 31)) & 1u) {
            int s = src[e + k];
            atomicOr(&bmP3[s >> 5], 1u << (s & 31));
            int p = atomicAdd(&cur[d], 1);
            csr[bbase[d >> BSHIFT] + rowptr2[d].x + p] = s;
        }
    }
}

// ---------------- hps = (x @ W1) * dis, only at P3 nodes ----------------
__global__ void mm1s_kernel(const float* __restrict__ x, const float* __restrict__ W1,
                            const unsigned int* __restrict__ bmP3,
                            const float* __restrict__ dis, float* __restrict__ hps) {
    __shared__ float w[F_IN * HID];
    for (int t = threadIdx.x; t < F_IN * HID; t += blockDim.x) w[t] = W1[t];
    __syncthreads();
    int row = blockIdx.x * blockDim.x + threadIdx.x;
    if (!((bmP3[row >> 5] >> (row & 31)) & 1u)) return;
    const float4* xr = (const float4*)(x + (size_t)row * F_IN);
    float acc[HID] = {0.f,0.f,0.f,0.f,0.f,0.f,0.f,0.f};
    #pragma unroll 8
    for (int it = 0; it < F_IN / 4; ++it) {
        float4 xv = xr[it];
        const float* wr = &w[it * 4 * HID];
        #pragma unroll
        for (int j = 0; j < HID; ++j)
            acc[j] += xv.x * wr[j] + xv.y * wr[HID + j] + xv.z * wr[2 * HID + j] + xv.w * wr[3 * HID + j];
    }
    float di = dis[row];
    float4* o = (float4*)(hps + (size_t)row * HID);
    o[0] = make_float4(acc[0] * di, acc[1] * di, acc[2] * di, acc[3] * di);
    o[1] = make_float4(acc[4] * di, acc[5] * di, acc[6] * di, acc[7] * di);
}

// ---- gather1 (P2 nodes): x1 = relu(di*(sum hps[s] + hps[i]) + b1);
//      hps2 = (x1 @ W2) * di; targets stash x1 row into x1t ------------------
__global__ void gather1_kernel(const int2* __restrict__ rowptr2, const int* __restrict__ bbase,
                               const int* __restrict__ csr,
                               const float* __restrict__ dis, const float* __restrict__ hps,
                               const unsigned int* __restrict__ bmP2,
                               const unsigned int* __restrict__ bmT,
                               const float* __restrict__ b1v, const float* __restrict__ W2,
                               float* __restrict__ hps2, float* __restrict__ x1t) {
    __shared__ float w[HID * HID];
    if (threadIdx.x < HID * HID) w[threadIdx.x] = W2[threadIdx.x];
    __syncthreads();
    int i = blockIdx.x * blockDim.x + threadIdx.x;
    if (!((bmP2[i >> 5] >> (i & 31)) & 1u)) return;
    float di = dis[i];
    int2 r = rowptr2[i];
    int bb = bbase[i >> BSHIFT];
    int e0 = bb + r.x, e1 = bb + r.y;
    float acc[HID] = {0.f,0.f,0.f,0.f,0.f,0.f,0.f,0.f};
    for (int k = e0; k < e1; ++k) {
        int s = csr[k];
        const float4* h = (const float4*)(hps + (size_t)s * HID);
        float4 a = h[0], b = h[1];
        acc[0] += a.x; acc[1] += a.y; acc[2] += a.z; acc[3] += a.w;
        acc[4] += b.x; acc[5] += b.y; acc[6] += b.z; acc[7] += b.w;
    }
    const float4* hs = (const float4*)(hps + (size_t)i * HID);
    float4 h0 = hs[0], h1 = hs[1];
    float v[HID];
    v[0] = fmaxf(di * (acc[0] + h0.x) + b1v[0], 0.f);
    v[1] = fmaxf(di * (acc[1] + h0.y) + b1v[1], 0.f);
    v[2] = fmaxf(di * (acc[2] + h0.z) + b1v[2], 0.f);
    v[3] = fmaxf(di * (acc[3] + h0.w) + b1v[3], 0.f);
    v[4] = fmaxf(di * (acc[4] + h1.x) + b1v[4], 0.f);
    v[5] = fmaxf(di * (acc[5] + h1.y) + b1v[5], 0.f);
    v[6] = fmaxf(di * (acc[6] + h1.z) + b1v[6], 0.f);
    v[7] = fmaxf(di * (acc[7] + h1.w) + b1v[7], 0.f);
    if ((bmT[i >> 5] >> (i & 31)) & 1u) {
        float* xt = x1t + (size_t)(i >> NPG_SHIFT) * HID;
        #pragma unroll
        for (int j = 0; j < HID; ++j) xt[j] = v[j];
    }
    float o[HID];
    #pragma unroll
    for (int j = 0; j < HID; ++j) {
        float sj = 0.f;
        #pragma unroll
        for (int k = 0; k < HID; ++k) sj += v[k] * w[k * HID + j];
        o[j] = sj * di;
    }
    float4* op = (float4*)(hps2 + (size_t)i * HID);
    op[0] = make_float4(o[0], o[1], o[2], o[3]);
    op[1] = make_float4(o[4], o[5], o[6], o[7]);
}

// ---- gather2 (P1 nodes): x2 = relu(di*(sum hps2[s] + hps2[i]) + b2) ----
__global__ void gather2_kernel(const int2* __restrict__ rowptr2, const int* __restrict__ bbase,
                               const int* __restrict__ csr,
                               const float* __restrict__ dis, const float* __restrict__ hps2,
                               const unsigned int* __restrict__ bmP1,
                               const float* __restrict__ b2v, float* __restrict__ x2) {
    int i = blockIdx.x * blockDim.x + threadIdx.x;
    if (!((bmP1[i >> 5] >> (i & 31)) & 1u)) return;
    float di = dis[i];
    int2 r = rowptr2[i];
    int bb = bbase[i >> BSHIFT];
    int e0 = bb + r.x, e1 = bb + r.y;
    float acc[HID] = {0.f,0.f,0.f,0.f,0.f,0.f,0.f,0.f};
    for (int k = e0; k < e1; ++k) {
        int s = csr[k];
        const float4* h = (const float4*)(hps2 + (size_t)s * HID);
        float4 a = h[0], b = h[1];
        acc[0] += a.x; acc[1] += a.y; acc[2] += a.z; acc[3] += a.w;
        acc[4] += b.x; acc[5] += b.y; acc[6] += b.z; acc[7] += b.w;
    }
    const float4* hs = (const float4*)(hps2 + (size_t)i * HID);
    float4 h0 = hs[0], h1 = hs[1];
    float4* xo = (float4*)(x2 + (size_t)i * HID);
    xo[0] = make_float4(fmaxf(di * (acc[0] + h0.x) + b2v[0], 0.f),
                        fmaxf(di * (acc[1] + h0.y) + b2v[1], 0.f),
                        fmaxf(di * (acc[2] + h0.z) + b2v[2], 0.f),
                        fmaxf(di * (acc[3] + h0.w) + b2v[3], 0.f));
    xo[1] = make_float4(fmaxf(di * (acc[4] + h1.x) + b2v[4], 0.f),
                        fmaxf(di * (acc[5] + h1.y) + b2v[5], 0.f),
                        fmaxf(di * (acc[6] + h1.z) + b2v[6], 0.f),
                        fmaxf(di * (acc[7] + h1.w) + b2v[7], 0.f));
}

// ---- head: x3 at target via csr row + feats + MLP ----
__global__ void headf_kernel(const int* __restrict__ tgt, const int2* __restrict__ rowptr2,
                             const int* __restrict__ bbase, const int* __restrict__ csr,
                             const float* __restrict__ dis,
                             const float* __restrict__ x1t, const float* __restrict__ x2,
                             const float* __restrict__ W3, const float* __restrict__ b3,
                             const float* __restrict__ Wl1, const float* __restrict__ bl1,
                             const float* __restrict__ Wl2, const float* __restrict__ bl2,
                             float* __restrict__ out) {
    int g = threadIdx.x;
    if (g >= B_GRAPHS) return;
    size_t t = (size_t)g * NPG + tgt[g];
    float di = dis[t];
    float w3[HID];
    #pragma unroll
    for (int j = 0; j < HID; ++j) w3[j] = W3[j];
    float f[17];
    #pragma unroll
    for (int j = 0; j < HID; ++j) f[j] = x1t[(size_t)g * HID + j];
    #pragma unroll
    for (int j = 0; j < HID; ++j) f[8 + j] = x2[t * HID + j];
    int2 r = rowptr2[t];
    int bb = bbase[t >> BSHIFT];
    float a3 = 0.f;
    for (int k = bb + r.x; k < bb + r.y; ++k) {
        int s = csr[k];
        float h = 0.f;
        #pragma unroll
        for (int j = 0; j < HID; ++j) h += x2[(size_t)s * HID + j] * w3[j];
        a3 += h * dis[s];
    }
    float h3 = 0.f;
    #pragma unroll
    for (int j = 0; j < HID; ++j) h3 += f[8 + j] * w3[j];
    f[16] = fmaxf(a3 * di + h3 * di * di + b3[0], 0.f);
    float o0 = bl2[0], o1 = bl2[1];
    #pragma unroll
    for (int j = 0; j < 16; ++j) {
        float z = bl1[j];
        #pragma unroll
        for (int k = 0; k < 17; ++k) z += f[k] * Wl1[k * 16 + j];
        z = fmaxf(z, 0.f);
        o0 += z * Wl2[j * 2 + 0];
        o1 += z * Wl2[j * 2 + 1];
    }
    out[g * 2 + 0] = o0;
    out[g * 2 + 1] = o1;
}

extern "C" void kernel_launch(void* const* d_in, const int* in_sizes, int n_in,
                              void* d_out, int out_size, void* d_ws, size_t ws_size,
                              hipStream_t stream) {
    const float* x  = (const float*)d_in[0];
    const int* ei   = (const int*)d_in[1];
    const int* src  = ei;
    const int* dst  = ei + E_EDGES;
    const int* tid  = (const int*)d_in[2];
    const float* W1 = (const float*)d_in[3];
    const float* b1 = (const float*)d_in[4];
    const float* W2 = (const float*)d_in[5];
    const float* b2 = (const float*)d_in[6];
    const float* W3 = (const float*)d_in[7];
    const float* b3 = (const float*)d_in[8];
    const float* Wl1 = (const float*)d_in[9];
    const float* bl1 = (const float*)d_in[10];
    const float* Wl2 = (const float*)d_in[11];
    const float* bl2 = (const float*)d_in[12];
    float* out = (float*)d_out;

    char* ws = (char*)d_ws;
    size_t off = 0;
    auto alloc = [&](size_t bytes) {
        void* p = ws + off;
        off += (bytes + 255) & ~(size_t)255;
        return p;
    };
    // cleared span (contiguous): 4 bitmaps 256 KB + cur 2 MB = 2.25 MB
    unsigned int* bmT  = (unsigned int*)alloc(65536);
    unsigned int* bmP1 = (unsigned int*)alloc(65536);
    unsigned int* bmP2 = (unsigned int*)alloc(65536);
    unsigned int* bmP3 = (unsigned int*)alloc(65536);
    int* cur = (int*)alloc((size_t)N_NODES * 4);                        // 2 MB
    const int CLEAR_INT4 = (4 * 65536 + N_NODES * 4) / 16;              // 147456
    // uncleared
    float* x1t   = (float*)alloc((size_t)B_GRAPHS * HID * 4);           // 2 KB
    int* sc      = (int*)alloc((size_t)BUCKETS * SBLK * 4);             // 512 KB
    int* btot    = (int*)alloc((size_t)BUCKETS * 4);
    int* bbase   = (int*)alloc((size_t)(BUCKETS + 1) * 4);
    int2* rowptr2 = (int2*)alloc((size_t)N_NODES * 8);                  // 4 MB
    float* dis   = (float*)alloc((size_t)N_NODES * 4);                  // 2 MB
    unsigned int* ebuf = (unsigned int*)alloc((size_t)BUCKETS * EB_STRIDE * 4); // 84 MB
    int* csr     = (int*)alloc((size_t)E_EDGES * 4);                    // 33.5 MB (sparse-filled)
    float* hps   = (float*)alloc((size_t)N_NODES * HID * 4);            // 16 MB
    float* hps2  = (float*)alloc((size_t)N_NODES * HID * 4);            // 16 MB
    float* x2 = hps;             // hps dead after gather1; reuse for x2
    (void)ws_size;

    clear_kernel<<<CLEAR_INT4 / 256, 256, 0, stream>>>((int4*)bmT);
    init_kernel<<<1, 64, 0, stream>>>(tid, bmT, bmP1, bmP2, bmP3);
    scatter_kernel<<<SBLK, STHREADS, 0, stream>>>(dst, ebuf, sc);
    count_kernel<<<BUCKETS, 256, 0, stream>>>(ebuf, sc, rowptr2, dis, btot);
    basescan_kernel<<<1, 256, 0, stream>>>(btot, bbase);
    sweep1_kernel<<<SWBLK, 256, 0, stream>>>(src, dst, bmT, bmP1, bmP2, bmP3);
    sweep2_kernel<<<SWBLK, 256, 0, stream>>>(src, dst, bmP1, bmP2, bmP3);
    sweep3_kernel<<<SWBLK, 256, 0, stream>>>(src, dst, bmP2, bmP3, rowptr2, bbase, cur, csr);
    mm1s_kernel<<<2048, 256, 0, stream>>>(x, W1, bmP3, dis, hps);
    gather1_kernel<<<2048, 256, 0, stream>>>(rowptr2, bbase, csr, dis, hps, bmP2, bmT, b1, W2, hps2, x1t);
    gather2_kernel<<<2048, 256, 0, stream>>>(rowptr2, bbase, csr, dis, hps2, bmP1, b2, x2);
    headf_kernel<<<1, 64, 0, stream>>>(tid, rowptr2, bbase, csr, dis, x1t, x2,
                                       W3, b3, Wl1, bl1, Wl2, bl2, out);
}

// Round 5
// 729.802 us; speedup vs baseline: 1.0738x; 1.0314x over previous
//
#include <hip/hip_runtime.h>
#include <cstdint>

#define N_NODES 524288
#define E_EDGES 8388608
#define F_IN 128
#define HID 8
#define B_GRAPHS 64
#define NPG 8192
#define NPG_SHIFT 13

// ---- bucketed counting-sort CSR build ----
#define BUCKETS 512
#define BSHIFT 10              // node >> 10 -> bucket
#define BNODES 1024            // nodes per bucket
#define LMASK 1023
#define SBLK 1024              // scatter blocks
#define STHREADS 512
#define EPB (E_EDGES / SBLK)   // 8192 edges per scatter block
#define CAP 64                 // per-(bucket,block) capacity (mean 16, +12 sigma)
#define EB_STRIDE (SBLK * CAP) // 65536 dwords per bucket
#define SBUF_CAP 18432         // max edges per bucket slice (mean 16384, +16 sigma)
#define CSR_CAP 18432          // csr dwords per bucket

// ---------------- clear bitmaps (256 KB) ----------------
__global__ void clear_kernel(int4* __restrict__ p) {
    p[blockIdx.x * blockDim.x + threadIdx.x] = make_int4(0, 0, 0, 0);
}

// ---- scatter: pack (local_dst,src) into per-(bucket,block) fixed-cap runs ----
__global__ __launch_bounds__(STHREADS) void scatter_kernel(
        const int* __restrict__ src, const int* __restrict__ dst,
        unsigned int* __restrict__ ebuf, int* __restrict__ sc) {
    __shared__ int cur[BUCKETS];
    int t = threadIdx.x;
    cur[t] = 0;                      // STHREADS == BUCKETS == 512
    __syncthreads();
    int eb = blockIdx.x * EPB;
    size_t blkoff = (size_t)blockIdx.x * CAP;
    #pragma unroll 4
    for (int k = 0; k < EPB / STHREADS; ++k) {
        int e = eb + k * STHREADS + t;
        int d = dst[e];
        int s = src[e];
        int b = d >> BSHIFT;
        int p = atomicAdd(&cur[b], 1);
        if (p < CAP)
            ebuf[(size_t)b * EB_STRIDE + blkoff + p] =
                ((unsigned int)(d & LMASK) << 19) | (unsigned int)s;
    }
    __syncthreads();
    sc[t * SBLK + blockIdx.x] = (cur[t] < CAP) ? cur[t] : CAP;
}

// ---- build: stage bucket slice in LDS, counting-sort, coalesced-window csr ----
__global__ __launch_bounds__(256) void build_kernel(const unsigned int* __restrict__ ebuf,
                                                    const int* __restrict__ sc,
                                                    int2* __restrict__ rowptr,
                                                    float* __restrict__ dis,
                                                    int* __restrict__ csr) {
    __shared__ int soff[SBLK];
    __shared__ unsigned int sbuf[SBUF_CAP];
    __shared__ int cnt[BNODES];
    __shared__ int cur[BNODES];
    __shared__ int tsum[256];
    __shared__ int ntot_s;
    int t = threadIdx.x;
    int b = blockIdx.x;
    // load this block's 4 sub-segment counts (consecutive -> int4)
    int4 c4 = ((const int4*)(sc + (size_t)b * SBLK))[t];
    int n0 = c4.x, n1 = c4.y, n2 = c4.z, n3 = c4.w;
    int s = n0 + n1 + n2 + n3;
    tsum[t] = s;
    cnt[t * 4 + 0] = 0; cnt[t * 4 + 1] = 0; cnt[t * 4 + 2] = 0; cnt[t * 4 + 3] = 0;
    __syncthreads();
    for (int o = 1; o < 256; o <<= 1) {
        int y = (t >= o) ? tsum[t - o] : 0;
        __syncthreads();
        tsum[t] += y;
        __syncthreads();
    }
    int off = (t == 0) ? 0 : tsum[t - 1];
    soff[t * 4 + 0] = off;
    soff[t * 4 + 1] = off + n0;
    soff[t * 4 + 2] = off + n0 + n1;
    soff[t * 4 + 3] = off + n0 + n1 + n2;
    if (t == 255) ntot_s = tsum[255];
    __syncthreads();
    // copy sub-segments into compact staging + fine count
    const unsigned int* eb = ebuf + (size_t)b * EB_STRIDE;
    #pragma unroll
    for (int k2 = 0; k2 < 4; ++k2) {
        int ss = t * 4 + k2;
        int n = (k2 == 0) ? n0 : (k2 == 1) ? n1 : (k2 == 2) ? n2 : n3;
        int so = soff[ss];
        if (so + n > SBUF_CAP) n = (SBUF_CAP > so) ? (SBUF_CAP - so) : 0;
        const unsigned int* p = eb + (size_t)ss * CAP;
        for (int k = 0; k < n; ++k) {
            unsigned int w = p[k];
            sbuf[so + k] = w;
            atomicAdd(&cnt[w >> 19], 1);
        }
    }
    __syncthreads();
    // exclusive scan of 1024 node counts, 4 per thread
    int v[4], loc[4], s2 = 0;
    #pragma unroll
    for (int k2 = 0; k2 < 4; ++k2) { v[k2] = cnt[t * 4 + k2]; loc[k2] = s2; s2 += v[k2]; }
    tsum[t] = s2;
    __syncthreads();
    for (int o = 1; o < 256; o <<= 1) {
        int y = (t >= o) ? tsum[t - o] : 0;
        __syncthreads();
        tsum[t] += y;
        __syncthreads();
    }
    int off2 = (t == 0) ? 0 : tsum[t - 1];
    int cbase = b * CSR_CAP;
    #pragma unroll
    for (int k2 = 0; k2 < 4; ++k2) {
        int j = t * 4 + k2;
        int st = off2 + loc[k2];
        cur[j] = st;
        rowptr[b * BNODES + j] = make_int2(cbase + st, cbase + st + v[k2]);
        dis[b * BNODES + j] = rsqrtf((float)v[k2] + 1.0f);
    }
    __syncthreads();
    // scatter: random 4B stores land in this block's 72 KB csr window (L2-held)
    int ntot = ntot_s;
    if (ntot > SBUF_CAP) ntot = SBUF_CAP;
    for (int k = t; k < ntot; k += 256) {
        unsigned int w = sbuf[k];
        int p = atomicAdd(&cur[w >> 19], 1);
        csr[cbase + p] = (int)(w & 0x7FFFFu);
    }
}

// ---------------- BFS1: targets -> planes, mark in-nbrs (P1) ----------------
__global__ void bfs1_kernel(const int* __restrict__ tgt, const int2* __restrict__ rowptr,
                            const int* __restrict__ csr,
                            unsigned int* __restrict__ bm1, unsigned int* __restrict__ bm2,
                            unsigned int* __restrict__ bm3, unsigned int* __restrict__ bmT) {
    int g = threadIdx.x;
    if (g >= B_GRAPHS) return;
    int t = g * NPG + tgt[g];
    atomicOr(&bmT[t >> 5], 1u << (t & 31));
    atomicOr(&bm1[t >> 5], 1u << (t & 31));
    atomicOr(&bm2[t >> 5], 1u << (t & 31));
    atomicOr(&bm3[t >> 5], 1u << (t & 31));
    int2 r = rowptr[t];
    for (int k = r.x; k < r.y; ++k) {
        int s = csr[k];
        atomicOr(&bm1[s >> 5], 1u << (s & 31));
        atomicOr(&bm2[s >> 5], 1u << (s & 31));
        atomicOr(&bm3[s >> 5], 1u << (s & 31));
    }
}

// ---------------- BFS2: plane1 nodes -> mark in-nbrs into planes 2,3 --------
__global__ void bfs2_kernel(const int2* __restrict__ rowptr, const int* __restrict__ csr,
                            const unsigned int* __restrict__ bm1,
                            unsigned int* __restrict__ bm2, unsigned int* __restrict__ bm3) {
    int i = blockIdx.x * blockDim.x + threadIdx.x;
    if (!((bm1[i >> 5] >> (i & 31)) & 1u)) return;
    int2 r = rowptr[i];
    for (int k = r.x; k < r.y; ++k) {
        int s = csr[k];
        atomicOr(&bm2[s >> 5], 1u << (s & 31));
        atomicOr(&bm3[s >> 5], 1u << (s & 31));
    }
}

// ---------------- BFS3: plane2 nodes -> mark in-nbrs into plane 3 -----------
__global__ void bfs3_kernel(const int2* __restrict__ rowptr, const int* __restrict__ csr,
                            const unsigned int* __restrict__ bm2,
                            unsigned int* __restrict__ bm3) {
    int i = blockIdx.x * blockDim.x + threadIdx.x;
    if (!((bm2[i >> 5] >> (i & 31)) & 1u)) return;
    int2 r = rowptr[i];
    for (int k = r.x; k < r.y; ++k) {
        int s = csr[k];
        atomicOr(&bm3[s >> 5], 1u << (s & 31));
    }
}

// ---------------- hps = (x @ W1) * dis, only at P3 nodes ----------------
__global__ void mm1s_kernel(const float* __restrict__ x, const float* __restrict__ W1,
                            const unsigned int* __restrict__ bm3,
                            const float* __restrict__ dis, float* __restrict__ hps) {
    __shared__ float w[F_IN * HID];
    for (int t = threadIdx.x; t < F_IN * HID; t += blockDim.x) w[t] = W1[t];
    __syncthreads();
    int row = blockIdx.x * blockDim.x + threadIdx.x;
    if (!((bm3[row >> 5] >> (row & 31)) & 1u)) return;
    const float4* xr = (const float4*)(x + (size_t)row * F_IN);
    float acc[HID] = {0.f,0.f,0.f,0.f,0.f,0.f,0.f,0.f};
    #pragma unroll 8
    for (int it = 0; it < F_IN / 4; ++it) {
        float4 xv = xr[it];
        const float* wr = &w[it * 4 * HID];
        #pragma unroll
        for (int j = 0; j < HID; ++j)
            acc[j] += xv.x * wr[j] + xv.y * wr[HID + j] + xv.z * wr[2 * HID + j] + xv.w * wr[3 * HID + j];
    }
    float di = dis[row];
    float4* o = (float4*)(hps + (size_t)row * HID);
    o[0] = make_float4(acc[0] * di, acc[1] * di, acc[2] * di, acc[3] * di);
    o[1] = make_float4(acc[4] * di, acc[5] * di, acc[6] * di, acc[7] * di);
}

// ---- gather1 (P2 nodes): x1 = relu(di*(sum hps[s] + hps[i]) + b1);
//      hps2 = (x1 @ W2) * di; targets stash x1 row into x1t ------------------
__global__ void gather1_kernel(const int2* __restrict__ rowptr, const int* __restrict__ csr,
                               const float* __restrict__ dis, const float* __restrict__ hps,
                               const unsigned int* __restrict__ bm2,
                               const unsigned int* __restrict__ bmT,
                               const float* __restrict__ b1v, const float* __restrict__ W2,
                               float* __restrict__ hps2, float* __restrict__ x1t) {
    __shared__ float w[HID * HID];
    if (threadIdx.x < HID * HID) w[threadIdx.x] = W2[threadIdx.x];
    __syncthreads();
    int i = blockIdx.x * blockDim.x + threadIdx.x;
    if (!((bm2[i >> 5] >> (i & 31)) & 1u)) return;
    float di = dis[i];
    int2 r = rowptr[i];
    float acc[HID] = {0.f,0.f,0.f,0.f,0.f,0.f,0.f,0.f};
    for (int k = r.x; k < r.y; ++k) {
        int s = csr[k];
        const float4* h = (const float4*)(hps + (size_t)s * HID);
        float4 a = h[0], b = h[1];
        acc[0] += a.x; acc[1] += a.y; acc[2] += a.z; acc[3] += a.w;
        acc[4] += b.x; acc[5] += b.y; acc[6] += b.z; acc[7] += b.w;
    }
    const float4* hs = (const float4*)(hps + (size_t)i * HID);
    float4 h0 = hs[0], h1 = hs[1];
    float v[HID];
    v[0] = fmaxf(di * (acc[0] + h0.x) + b1v[0], 0.f);
    v[1] = fmaxf(di * (acc[1] + h0.y) + b1v[1], 0.f);
    v[2] = fmaxf(di * (acc[2] + h0.z) + b1v[2], 0.f);
    v[3] = fmaxf(di * (acc[3] + h0.w) + b1v[3], 0.f);
    v[4] = fmaxf(di * (acc[4] + h1.x) + b1v[4], 0.f);
    v[5] = fmaxf(di * (acc[5] + h1.y) + b1v[5], 0.f);
    v[6] = fmaxf(di * (acc[6] + h1.z) + b1v[6], 0.f);
    v[7] = fmaxf(di * (acc[7] + h1.w) + b1v[7], 0.f);
    if ((bmT[i >> 5] >> (i & 31)) & 1u) {
        float* xt = x1t + (size_t)(i >> NPG_SHIFT) * HID;
        #pragma unroll
        for (int j = 0; j < HID; ++j) xt[j] = v[j];
    }
    float o[HID];
    #pragma unroll
    for (int j = 0; j < HID; ++j) {
        float sj = 0.f;
        #pragma unroll
        for (int k = 0; k < HID; ++k) sj += v[k] * w[k * HID + j];
        o[j] = sj * di;
    }
    float4* op = (float4*)(hps2 + (size_t)i * HID);
    op[0] = make_float4(o[0], o[1], o[2], o[3]);
    op[1] = make_float4(o[4], o[5], o[6], o[7]);
}

// ---- gather2 (P1 nodes): x2 = relu(di*(sum hps2[s] + hps2[i]) + b2) ----
__global__ void gather2_kernel(const int2* __restrict__ rowptr, const int* __restrict__ csr,
                               const float* __restrict__ dis, const float* __restrict__ hps2,
                               const unsigned int* __restrict__ bm1,
                               const float* __restrict__ b2v, float* __restrict__ x2) {
    int i = blockIdx.x * blockDim.x + threadIdx.x;
    if (!((bm1[i >> 5] >> (i & 31)) & 1u)) return;
    float di = dis[i];
    int2 r = rowptr[i];
    float acc[HID] = {0.f,0.f,0.f,0.f,0.f,0.f,0.f,0.f};
    for (int k = r.x; k < r.y; ++k) {
        int s = csr[k];
        const float4* h = (const float4*)(hps2 + (size_t)s * HID);
        float4 a = h[0], b = h[1];
        acc[0] += a.x; acc[1] += a.y; acc[2] += a.z; acc[3] += a.w;
        acc[4] += b.x; acc[5] += b.y; acc[6] += b.z; acc[7] += b.w;
    }
    const float4* hs = (const float4*)(hps2 + (size_t)i * HID);
    float4 h0 = hs[0], h1 = hs[1];
    float4* xo = (float4*)(x2 + (size_t)i * HID);
    xo[0] = make_float4(fmaxf(di * (acc[0] + h0.x) + b2v[0], 0.f),
                        fmaxf(di * (acc[1] + h0.y) + b2v[1], 0.f),
                        fmaxf(di * (acc[2] + h0.z) + b2v[2], 0.f),
                        fmaxf(di * (acc[3] + h0.w) + b2v[3], 0.f));
    xo[1] = make_float4(fmaxf(di * (acc[4] + h1.x) + b2v[4], 0.f),
                        fmaxf(di * (acc[5] + h1.y) + b2v[5], 0.f),
                        fmaxf(di * (acc[6] + h1.z) + b2v[6], 0.f),
                        fmaxf(di * (acc[7] + h1.w) + b2v[7], 0.f));
}

// ---- head: x3 at target via csr row + feats + MLP ----
__global__ void headf_kernel(const int* __restrict__ tgt, const int2* __restrict__ rowptr,
                             const int* __restrict__ csr, const float* __restrict__ dis,
                             const float* __restrict__ x1t, const float* __restrict__ x2,
                             const float* __restrict__ W3, const float* __restrict__ b3,
                             const float* __restrict__ Wl1, const float* __restrict__ bl1,
                             const float* __restrict__ Wl2, const float* __restrict__ bl2,
                             float* __restrict__ out) {
    int g = threadIdx.x;
    if (g >= B_GRAPHS) return;
    size_t t = (size_t)g * NPG + tgt[g];
    float di = dis[t];
    float w3[HID];
    #pragma unroll
    for (int j = 0; j < HID; ++j) w3[j] = W3[j];
    float f[17];
    #pragma unroll
    for (int j = 0; j < HID; ++j) f[j] = x1t[(size_t)g * HID + j];
    #pragma unroll
    for (int j = 0; j < HID; ++j) f[8 + j] = x2[t * HID + j];
    int2 r = rowptr[t];
    float a3 = 0.f;
    for (int k = r.x; k < r.y; ++k) {
        int s = csr[k];
        float h = 0.f;
        #pragma unroll
        for (int j = 0; j < HID; ++j) h += x2[(size_t)s * HID + j] * w3[j];
        a3 += h * dis[s];
    }
    float h3 = 0.f;
    #pragma unroll
    for (int j = 0; j < HID; ++j) h3 += f[8 + j] * w3[j];
    f[16] = fmaxf(a3 * di + h3 * di * di + b3[0], 0.f);
    float o0 = bl2[0], o1 = bl2[1];
    #pragma unroll
    for (int j = 0; j < 16; ++j) {
        float z = bl1[j];
        #pragma unroll
        for (int k = 0; k < 17; ++k) z += f[k] * Wl1[k * 16 + j];
        z = fmaxf(z, 0.f);
        o0 += z * Wl2[j * 2 + 0];
        o1 += z * Wl2[j * 2 + 1];
    }
    out[g * 2 + 0] = o0;
    out[g * 2 + 1] = o1;
}

extern "C" void kernel_launch(void* const* d_in, const int* in_sizes, int n_in,
                              void* d_out, int out_size, void* d_ws, size_t ws_size,
                              hipStream_t stream) {
    const float* x  = (const float*)d_in[0];
    const int* ei   = (const int*)d_in[1];
    const int* src  = ei;
    const int* dst  = ei + E_EDGES;
    const int* tid  = (const int*)d_in[2];
    const float* W1 = (const float*)d_in[3];
    const float* b1 = (const float*)d_in[4];
    const float* W2 = (const float*)d_in[5];
    const float* b2 = (const float*)d_in[6];
    const float* W3 = (const float*)d_in[7];
    const float* b3 = (const float*)d_in[8];
    const float* Wl1 = (const float*)d_in[9];
    const float* bl1 = (const float*)d_in[10];
    const float* Wl2 = (const float*)d_in[11];
    const float* bl2 = (const float*)d_in[12];
    float* out = (float*)d_out;

    char* ws = (char*)d_ws;
    size_t off = 0;
    auto alloc = [&](size_t bytes) {
        void* p = ws + off;
        off += (bytes + 255) & ~(size_t)255;
        return p;
    };
    // cleared span (contiguous): 4 bitmaps = 256 KB
    unsigned int* bmT  = (unsigned int*)alloc(65536);
    unsigned int* bmP1 = (unsigned int*)alloc(65536);
    unsigned int* bmP2 = (unsigned int*)alloc(65536);
    unsigned int* bmP3 = (unsigned int*)alloc(65536);
    // uncleared
    float* x1t   = (float*)alloc((size_t)B_GRAPHS * HID * 4);            // 2 KB
    int* sc      = (int*)alloc((size_t)BUCKETS * SBLK * 4);              // 2 MB
    int2* rowptr = (int2*)alloc((size_t)N_NODES * 8);                    // 4 MB
    float* dis   = (float*)alloc((size_t)N_NODES * 4);                   // 2 MB
    unsigned int* ebuf = (unsigned int*)alloc((size_t)BUCKETS * EB_STRIDE * 4); // 134 MB
    int* csr     = (int*)alloc((size_t)BUCKETS * CSR_CAP * 4);           // 37.75 MB
    float* hps   = (float*)alloc((size_t)N_NODES * HID * 4);             // 16 MB
    float* hps2  = (float*)alloc((size_t)N_NODES * HID * 4);             // 16 MB
    float* x2 = hps;             // hps dead after gather1; reuse for x2
    (void)ws_size;

    clear_kernel<<<64, 256, 0, stream>>>((int4*)bmT);
    scatter_kernel<<<SBLK, STHREADS, 0, stream>>>(src, dst, ebuf, sc);
    build_kernel<<<BUCKETS, 256, 0, stream>>>(ebuf, sc, rowptr, dis, csr);
    bfs1_kernel<<<1, 64, 0, stream>>>(tid, rowptr, csr, bmP1, bmP2, bmP3, bmT);
    bfs2_kernel<<<2048, 256, 0, stream>>>(rowptr, csr, bmP1, bmP2, bmP3);
    bfs3_kernel<<<2048, 256, 0, stream>>>(rowptr, csr, bmP2, bmP3);
    mm1s_kernel<<<2048, 256, 0, stream>>>(x, W1, bmP3, dis, hps);
    gather1_kernel<<<2048, 256, 0, stream>>>(rowptr, csr, dis, hps, bmP2, bmT, b1, W2, hps2, x1t);
    gather2_kernel<<<2048, 256, 0, stream>>>(rowptr, csr, dis, hps2, bmP1, b2, x2);
    headf_kernel<<<1, 64, 0, stream>>>(tid, rowptr, csr, dis, x1t, x2,
                                       W3, b3, Wl1, bl1, Wl2, bl2, out);
}